// Round 1
// baseline (548.619 us; speedup 1.0000x reference)
//
#include <hip/hip_runtime.h>
#include <hip/hip_bf16.h>

// ---------------------------------------------------------------------------
// TransformerBlock: LN1 -> fused QKV GEMM -> flash causal MHA -> Wo GEMM (+x)
//                   -> LN2 -> FF1 GEMM (+b1, exact GELU) -> FF2 GEMM (+x2)
// B=2, T=2048, D=1024, H=16, K=64, DFF=4096. fp32 I/O, bf16 MFMA internally.
// ---------------------------------------------------------------------------

#define BT   4096   // B*T rows
#define DIM  1024
#define DFF  4096
#define TSEQ 2048
#define NHEAD 16
#define HDIM 64
#define QKV_LD 3072

typedef __attribute__((ext_vector_type(8))) short  bf16x8;
typedef __attribute__((ext_vector_type(4))) float  floatx4;

__device__ __forceinline__ void async_copy16(const __hip_bfloat16* g, __hip_bfloat16* l) {
    __builtin_amdgcn_global_load_lds(
        (const __attribute__((address_space(1))) void*)g,
        (__attribute__((address_space(3))) void*)l, 16, 0, 0);
}

// ---------------------------------------------------------------------------
// LayerNorm: fp32 in -> bf16 out.  One block (256 thr) per row of 1024.
// ---------------------------------------------------------------------------
__global__ __launch_bounds__(256) void ln_kernel(const float* __restrict__ x,
                                                 const float* __restrict__ g,
                                                 const float* __restrict__ be,
                                                 __hip_bfloat16* __restrict__ out) {
    const int row = blockIdx.x;
    const int t = threadIdx.x;
    const float4 v = ((const float4*)(x + (size_t)row * DIM))[t];
    float s  = v.x + v.y + v.z + v.w;
    float ss = v.x * v.x + v.y * v.y + v.z * v.z + v.w * v.w;
    for (int d = 1; d < 64; d <<= 1) { s += __shfl_xor(s, d); ss += __shfl_xor(ss, d); }
    __shared__ float red[8];
    const int w = t >> 6;
    if ((t & 63) == 0) { red[w] = s; red[w + 4] = ss; }
    __syncthreads();
    s  = red[0] + red[1] + red[2] + red[3];
    ss = red[4] + red[5] + red[6] + red[7];
    const float mu = s * (1.0f / DIM);
    const float rstd = rsqrtf(ss * (1.0f / DIM) - mu * mu + 1e-5f);
    const float4 gv = ((const float4*)g)[t];
    const float4 bv = ((const float4*)be)[t];
    __hip_bfloat16* o = out + (size_t)row * DIM + t * 4;
    o[0] = __float2bfloat16((v.x - mu) * rstd * gv.x + bv.x);
    o[1] = __float2bfloat16((v.y - mu) * rstd * gv.y + bv.y);
    o[2] = __float2bfloat16((v.z - mu) * rstd * gv.z + bv.z);
    o[3] = __float2bfloat16((v.w - mu) * rstd * gv.w + bv.w);
}

// ---------------------------------------------------------------------------
// Generic 64x64-tile transpose+cast: dst[c][r] = (bf16)src[r][c]
// grid.x = row tiles of src, grid.y = col tiles of src
// ---------------------------------------------------------------------------
__global__ __launch_bounds__(256) void transpose_cast(const float* __restrict__ src, int src_ld,
                                                      __hip_bfloat16* __restrict__ dst, int dst_ld) {
    __shared__ float tile[64][65];
    const int r0 = blockIdx.x * 64, c0 = blockIdx.y * 64;
    const int tr = threadIdx.x >> 6;   // 0..3
    const int tc = threadIdx.x & 63;   // 0..63
    for (int i = 0; i < 16; ++i) {
        const int r = i * 4 + tr;
        tile[r][tc] = src[(size_t)(r0 + r) * src_ld + c0 + tc];
    }
    __syncthreads();
    for (int i = 0; i < 16; ++i) {
        const int c = i * 4 + tr;
        dst[(size_t)(c0 + c) * dst_ld + r0 + tc] = __float2bfloat16(tile[tc][c]);
    }
}

// Wq/Wk/Wv [H][D][64] fp32 -> WqkvT [3072][1024] bf16, row n = proj*1024+h*64+k
__global__ __launch_bounds__(256) void transpose_qkv(const float* __restrict__ Wq,
                                                     const float* __restrict__ Wk,
                                                     const float* __restrict__ Wv,
                                                     __hip_bfloat16* __restrict__ dst) {
    __shared__ float tile[64][65];
    const int hz = blockIdx.y;            // 0..47
    const int proj = hz >> 4, h = hz & 15;
    const float* W = (proj == 0 ? Wq : (proj == 1 ? Wk : Wv)) + (size_t)h * DIM * HDIM;
    const int r0 = blockIdx.x * 64;       // d tile
    const int tr = threadIdx.x >> 6;
    const int tc = threadIdx.x & 63;
    for (int i = 0; i < 16; ++i) {
        const int r = i * 4 + tr;
        tile[r][tc] = W[(size_t)(r0 + r) * HDIM + tc];
    }
    __syncthreads();
    for (int i = 0; i < 16; ++i) {
        const int k = i * 4 + tr;
        dst[(size_t)(proj * 1024 + h * 64 + k) * DIM + r0 + tc] = __float2bfloat16(tile[tc][k]);
    }
}

// ---------------------------------------------------------------------------
// bf16 GEMM  C[M,N] = A[M,K] * Bt[N,K]^T   (m97 structure)
// EPI 0: outb = bf16(acc)
// EPI 1: outb = bf16(gelu(acc + bias[col]))
// EPI 2: outf = resid + acc + bias[col]   (fp32)
// ---------------------------------------------------------------------------
template <int EPI>
__global__ __launch_bounds__(256) void gemm_bt(const __hip_bfloat16* __restrict__ A,
                                               const __hip_bfloat16* __restrict__ Bt,
                                               __hip_bfloat16* __restrict__ outb,
                                               float* __restrict__ outf,
                                               const float* __restrict__ bias,
                                               const float* __restrict__ resid,
                                               int M, int N, int K) {
    __shared__ __align__(16) __hip_bfloat16 As[128 * 32];
    __shared__ __align__(16) __hip_bfloat16 Bs[128 * 32];
    const int t = threadIdx.x;
    const int w = t >> 6, l = t & 63;
    const int quad = l >> 4, tl = l & 15;
    const int wr = w >> 1, wc = w & 1;
    const int m0 = blockIdx.y * 128, n0 = blockIdx.x * 128;

    floatx4 acc[4][4] = {};

    const int rowA = t >> 2;          // 0..63 (round 0), +64 (round 1)
    const int c8 = (t & 3) << 3;

    for (int k0 = 0; k0 < K; k0 += 32) {
        __syncthreads();
        {
            const __hip_bfloat16* gA = A + (size_t)(m0 + rowA) * K + k0 + c8;
            const __hip_bfloat16* gB = Bt + (size_t)(n0 + rowA) * K + k0 + c8;
            async_copy16(gA,                    As + w * 512);
            async_copy16(gA + (size_t)64 * K,   As + 2048 + w * 512);
            async_copy16(gB,                    Bs + w * 512);
            async_copy16(gB + (size_t)64 * K,   Bs + 2048 + w * 512);
        }
        __syncthreads();

        bf16x8 af[4], bfr[4];
        const int aRow = wr * 64 + tl;
        const int bRow = wc * 64 + tl;
        for (int mi = 0; mi < 4; ++mi)
            af[mi] = *(const bf16x8*)(As + (aRow + mi * 16) * 32 + quad * 8);
        for (int ni = 0; ni < 4; ++ni)
            bfr[ni] = *(const bf16x8*)(Bs + (bRow + ni * 16) * 32 + quad * 8);
        for (int mi = 0; mi < 4; ++mi)
            for (int ni = 0; ni < 4; ++ni)
                acc[mi][ni] = __builtin_amdgcn_mfma_f32_16x16x32_bf16(af[mi], bfr[ni], acc[mi][ni], 0, 0, 0);
    }

    const int rowBase = m0 + wr * 64 + quad * 4;
    const int colBase = n0 + wc * 64 + tl;
    for (int mi = 0; mi < 4; ++mi) {
        for (int ni = 0; ni < 4; ++ni) {
            const int c = colBase + ni * 16;
            for (int j = 0; j < 4; ++j) {
                const int r = rowBase + mi * 16 + j;
                const size_t idx = (size_t)r * N + c;
                float v = acc[mi][ni][j];
                if (EPI == 0) {
                    outb[idx] = __float2bfloat16(v);
                } else if (EPI == 1) {
                    v += bias[c];
                    v = 0.5f * v * (1.0f + erff(v * 0.70710678118654752f));
                    outb[idx] = __float2bfloat16(v);
                } else {
                    outf[idx] = resid[idx] + v + bias[c];
                }
            }
        }
    }
}

// ---------------------------------------------------------------------------
// Flash causal attention. qkv bf16 [B*T][3072] (q|k|v per head-64 chunks).
// One wave per (b, h, 16 q-rows). Online softmax in exp2 domain.
// out bf16 [B*T][1024] (head-concat layout), ready as GEMM A operand.
// ---------------------------------------------------------------------------
__global__ __launch_bounds__(256) void attn_kernel(const __hip_bfloat16* __restrict__ qkv,
                                                   __hip_bfloat16* __restrict__ out) {
    __shared__ __align__(16) __hip_bfloat16 Plds[4][16 * 32];
    const int t = threadIdx.x;
    const int w = t >> 6, l = t & 63;
    const int quad = l >> 4, tl = l & 15;
    const int wgid = blockIdx.x * 4 + w;     // 0..4095
    const int qt = wgid & 127;               // q tile
    const int bh = wgid >> 7;                // 0..31
    const int b = bh >> 4, h = bh & 15;
    const int q0 = qt * 16;
    const size_t base = (size_t)b * TSEQ * QKV_LD;
    const __hip_bfloat16* Q  = qkv + base + h * HDIM;
    const __hip_bfloat16* Kp = Q + 1024;
    const __hip_bfloat16* Vp = Q + 2048;

    bf16x8 qf0, qf1;
    {
        const __hip_bfloat16* qrow = Q + (size_t)(q0 + tl) * QKV_LD + quad * 8;
        qf0 = *(const bf16x8*)qrow;
        qf1 = *(const bf16x8*)(qrow + 32);
    }
    float m_i[4], l_i[4];
    floatx4 oacc[4] = {};
    for (int j = 0; j < 4; ++j) { m_i[j] = -1e30f; l_i[j] = 0.0f; }
    const float cscale = 0.125f * 1.4426950408889634f;  // k^-0.5 * log2(e)
    const int nfull = q0 >> 5;
    __hip_bfloat16* P = Plds[w];

    for (int it = 0; it <= nfull; ++it) {
        const int s0 = it * 32;
        const bool masked = (it == nfull);
        floatx4 sc0 = {}, sc1 = {};
        {
            const __hip_bfloat16* krow = Kp + (size_t)(s0 + tl) * QKV_LD + quad * 8;
            bf16x8 kf0 = *(const bf16x8*)krow;
            bf16x8 kf1 = *(const bf16x8*)(krow + 32);
            sc0 = __builtin_amdgcn_mfma_f32_16x16x32_bf16(qf0, kf0, sc0, 0, 0, 0);
            sc0 = __builtin_amdgcn_mfma_f32_16x16x32_bf16(qf1, kf1, sc0, 0, 0, 0);
            const __hip_bfloat16* krow2 = krow + (size_t)16 * QKV_LD;
            bf16x8 kf2 = *(const bf16x8*)krow2;
            bf16x8 kf3 = *(const bf16x8*)(krow2 + 32);
            sc1 = __builtin_amdgcn_mfma_f32_16x16x32_bf16(qf0, kf2, sc1, 0, 0, 0);
            sc1 = __builtin_amdgcn_mfma_f32_16x16x32_bf16(qf1, kf3, sc1, 0, 0, 0);
        }
        float p0[4], p1[4], alpha[4];
        for (int j = 0; j < 4; ++j) {
            float a  = sc0[j] * cscale;
            float bb = sc1[j] * cscale;
            if (masked) {
                const int r = q0 + quad * 4 + j;
                if (s0 + tl > r)      a  = -1e30f;
                if (s0 + 16 + tl > r) bb = -1e30f;
            }
            p0[j] = a; p1[j] = bb;
        }
        for (int j = 0; j < 4; ++j) {
            float tm = fmaxf(p0[j], p1[j]);
            tm = fmaxf(tm, __shfl_xor(tm, 1));
            tm = fmaxf(tm, __shfl_xor(tm, 2));
            tm = fmaxf(tm, __shfl_xor(tm, 4));
            tm = fmaxf(tm, __shfl_xor(tm, 8));
            const float mn = fmaxf(m_i[j], tm);
            alpha[j] = exp2f(m_i[j] - mn);
            m_i[j] = mn;
            p0[j] = exp2f(p0[j] - mn);
            p1[j] = exp2f(p1[j] - mn);
            float ps = p0[j] + p1[j];
            ps += __shfl_xor(ps, 1);
            ps += __shfl_xor(ps, 2);
            ps += __shfl_xor(ps, 4);
            ps += __shfl_xor(ps, 8);
            l_i[j] = l_i[j] * alpha[j] + ps;
        }
        for (int ni = 0; ni < 4; ++ni)
            for (int j = 0; j < 4; ++j)
                oacc[ni][j] *= alpha[j];
        // P (C-layout) -> LDS -> A-layout (m120-verified round trip)
        for (int j = 0; j < 4; ++j) {
            P[(quad * 4 + j) * 32 + tl]      = __float2bfloat16(p0[j]);
            P[(quad * 4 + j) * 32 + 16 + tl] = __float2bfloat16(p1[j]);
        }
        __builtin_amdgcn_wave_barrier();   // keep compiler from reordering LDS ops
        bf16x8 pf = *(const bf16x8*)(P + tl * 32 + quad * 8);
        const unsigned short* Vs = (const unsigned short*)Vp;
        for (int ni = 0; ni < 4; ++ni) {
            bf16x8 vf;
            const size_t vcol = ni * 16 + tl;
            for (int jj = 0; jj < 8; ++jj)
                vf[jj] = (short)Vs[(size_t)(s0 + quad * 8 + jj) * QKV_LD + vcol];
            oacc[ni] = __builtin_amdgcn_mfma_f32_16x16x32_bf16(pf, vf, oacc[ni], 0, 0, 0);
        }
    }

    for (int j = 0; j < 4; ++j) {
        const float inv = 1.0f / l_i[j];
        const int r = q0 + quad * 4 + j;
        __hip_bfloat16* orow = out + ((size_t)b * TSEQ + r) * DIM + h * HDIM;
        for (int ni = 0; ni < 4; ++ni)
            orow[ni * 16 + tl] = __float2bfloat16(oacc[ni][j] * inv);
    }
}

// ---------------------------------------------------------------------------
extern "C" void kernel_launch(void* const* d_in, const int* in_sizes, int n_in,
                              void* d_out, int out_size, void* d_ws, size_t ws_size,
                              hipStream_t stream) {
    const float* x   = (const float*)d_in[0];
    const float* Wq  = (const float*)d_in[1];
    const float* Wk  = (const float*)d_in[2];
    const float* Wv  = (const float*)d_in[3];
    const float* Wo  = (const float*)d_in[4];
    const float* bo  = (const float*)d_in[5];
    const float* W1  = (const float*)d_in[6];
    const float* b1  = (const float*)d_in[7];
    const float* W2  = (const float*)d_in[8];
    const float* b2  = (const float*)d_in[9];
    const float* g1  = (const float*)d_in[10];
    const float* be1 = (const float*)d_in[11];
    const float* g2  = (const float*)d_in[12];
    const float* be2 = (const float*)d_in[13];
    float* out = (float*)d_out;

    size_t off = 0;
    char* wsb = (char*)d_ws;
    auto carve = [&](size_t bytes) {
        void* p = wsb + off;
        off += (bytes + 255) & ~(size_t)255;
        return p;
    };
    __hip_bfloat16* WqkvT = (__hip_bfloat16*)carve((size_t)3072 * 1024 * 2);
    __hip_bfloat16* WoT   = (__hip_bfloat16*)carve((size_t)1024 * 1024 * 2);
    __hip_bfloat16* W1T   = (__hip_bfloat16*)carve((size_t)4096 * 1024 * 2);
    __hip_bfloat16* W2T   = (__hip_bfloat16*)carve((size_t)1024 * 4096 * 2);
    __hip_bfloat16* h1    = (__hip_bfloat16*)carve((size_t)BT * DIM * 2);
    __hip_bfloat16* qkv   = (__hip_bfloat16*)carve((size_t)BT * QKV_LD * 2);
    __hip_bfloat16* att   = (__hip_bfloat16*)carve((size_t)BT * DIM * 2);
    float*          x2    = (float*)carve((size_t)BT * DIM * 4);
    __hip_bfloat16* h2    = (__hip_bfloat16*)carve((size_t)BT * DIM * 2);
    __hip_bfloat16* ff1   = (__hip_bfloat16*)carve((size_t)BT * DFF * 2);

    // weight prep
    transpose_qkv<<<dim3(16, 48), 256, 0, stream>>>(Wq, Wk, Wv, WqkvT);
    transpose_cast<<<dim3(16, 16), 256, 0, stream>>>(Wo, 1024, WoT, 1024);
    transpose_cast<<<dim3(16, 64), 256, 0, stream>>>(W1, 4096, W1T, 1024);
    transpose_cast<<<dim3(64, 16), 256, 0, stream>>>(W2, 1024, W2T, 4096);

    // LN1
    ln_kernel<<<BT, 256, 0, stream>>>(x, g1, be1, h1);
    // fused QKV projection: [4096,1024] x [3072,1024]^T -> bf16 [4096,3072]
    gemm_bt<0><<<dim3(24, 32), 256, 0, stream>>>(h1, WqkvT, qkv, nullptr, nullptr, nullptr,
                                                 BT, QKV_LD, DIM);
    // causal MHA
    attn_kernel<<<1024, 256, 0, stream>>>(qkv, att);
    // x2 = x + att @ Wo + bo   (fp32)
    gemm_bt<2><<<dim3(8, 32), 256, 0, stream>>>(att, WoT, nullptr, x2, bo, x,
                                                BT, DIM, DIM);
    // LN2
    ln_kernel<<<BT, 256, 0, stream>>>(x2, g2, be2, h2);
    // ff = gelu(h2 @ W1 + b1)  bf16 [4096,4096]
    gemm_bt<1><<<dim3(32, 32), 256, 0, stream>>>(h2, W1T, ff1, nullptr, b1, nullptr,
                                                 BT, DFF, DIM);
    // out = x2 + ff @ W2 + b2  (fp32)
    gemm_bt<2><<<dim3(8, 32), 256, 0, stream>>>(ff1, W2T, nullptr, out, b2, x2,
                                                BT, DIM, DFF);
}

// Round 2
// 517.885 us; speedup vs baseline: 1.0593x; 1.0593x over previous
//
#include <hip/hip_runtime.h>
#include <hip/hip_bf16.h>

// ---------------------------------------------------------------------------
// TransformerBlock: LN1 -> fused QKV GEMM -> flash causal MHA -> Wo GEMM (+x)
//                   -> LN2 -> FF1 GEMM (+b1, exact GELU) -> FF2 GEMM (+x2)
// B=2, T=2048, D=1024, H=16, K=64, DFF=4096. fp32 I/O, bf16 MFMA internally.
// ---------------------------------------------------------------------------

#define BT   4096   // B*T rows
#define DIM  1024
#define DFF  4096
#define TSEQ 2048
#define NHEAD 16
#define HDIM 64
#define QKV_LD 3072

typedef __attribute__((ext_vector_type(8))) short  bf16x8;
typedef __attribute__((ext_vector_type(4))) short  bf16x4;
typedef __attribute__((ext_vector_type(4))) float  floatx4;

__device__ __forceinline__ void async_copy16(const __hip_bfloat16* g, __hip_bfloat16* l) {
    __builtin_amdgcn_global_load_lds(
        (const __attribute__((address_space(1))) void*)g,
        (__attribute__((address_space(3))) void*)l, 16, 0, 0);
}

// ---------------------------------------------------------------------------
// LayerNorm: fp32 in -> bf16 out.  One block (256 thr) per row of 1024.
// ---------------------------------------------------------------------------
__global__ __launch_bounds__(256) void ln_kernel(const float* __restrict__ x,
                                                 const float* __restrict__ g,
                                                 const float* __restrict__ be,
                                                 __hip_bfloat16* __restrict__ out) {
    const int row = blockIdx.x;
    const int t = threadIdx.x;
    const float4 v = ((const float4*)(x + (size_t)row * DIM))[t];
    float s  = v.x + v.y + v.z + v.w;
    float ss = v.x * v.x + v.y * v.y + v.z * v.z + v.w * v.w;
    for (int d = 1; d < 64; d <<= 1) { s += __shfl_xor(s, d); ss += __shfl_xor(ss, d); }
    __shared__ float red[8];
    const int w = t >> 6;
    if ((t & 63) == 0) { red[w] = s; red[w + 4] = ss; }
    __syncthreads();
    s  = red[0] + red[1] + red[2] + red[3];
    ss = red[4] + red[5] + red[6] + red[7];
    const float mu = s * (1.0f / DIM);
    const float rstd = rsqrtf(ss * (1.0f / DIM) - mu * mu + 1e-5f);
    const float4 gv = ((const float4*)g)[t];
    const float4 bv = ((const float4*)be)[t];
    __hip_bfloat16* o = out + (size_t)row * DIM + t * 4;
    o[0] = __float2bfloat16((v.x - mu) * rstd * gv.x + bv.x);
    o[1] = __float2bfloat16((v.y - mu) * rstd * gv.y + bv.y);
    o[2] = __float2bfloat16((v.z - mu) * rstd * gv.z + bv.z);
    o[3] = __float2bfloat16((v.w - mu) * rstd * gv.w + bv.w);
}

// ---------------------------------------------------------------------------
// Generic 64x64-tile transpose+cast: dst[c][r] = (bf16)src[r][c]
// ---------------------------------------------------------------------------
__global__ __launch_bounds__(256) void transpose_cast(const float* __restrict__ src, int src_ld,
                                                      __hip_bfloat16* __restrict__ dst, int dst_ld) {
    __shared__ float tile[64][65];
    const int r0 = blockIdx.x * 64, c0 = blockIdx.y * 64;
    const int tr = threadIdx.x >> 6;   // 0..3
    const int tc = threadIdx.x & 63;   // 0..63
    for (int i = 0; i < 16; ++i) {
        const int r = i * 4 + tr;
        tile[r][tc] = src[(size_t)(r0 + r) * src_ld + c0 + tc];
    }
    __syncthreads();
    for (int i = 0; i < 16; ++i) {
        const int c = i * 4 + tr;
        dst[(size_t)(c0 + c) * dst_ld + r0 + tc] = __float2bfloat16(tile[tc][c]);
    }
}

// Wq/Wk/Wv [H][D][64] fp32 -> WqkvT [3072][1024] bf16, row n = proj*1024+h*64+k
__global__ __launch_bounds__(256) void transpose_qkv(const float* __restrict__ Wq,
                                                     const float* __restrict__ Wk,
                                                     const float* __restrict__ Wv,
                                                     __hip_bfloat16* __restrict__ dst) {
    __shared__ float tile[64][65];
    const int hz = blockIdx.y;            // 0..47
    const int proj = hz >> 4, h = hz & 15;
    const float* W = (proj == 0 ? Wq : (proj == 1 ? Wk : Wv)) + (size_t)h * DIM * HDIM;
    const int r0 = blockIdx.x * 64;       // d tile
    const int tr = threadIdx.x >> 6;
    const int tc = threadIdx.x & 63;
    for (int i = 0; i < 16; ++i) {
        const int r = i * 4 + tr;
        tile[r][tc] = W[(size_t)(r0 + r) * HDIM + tc];
    }
    __syncthreads();
    for (int i = 0; i < 16; ++i) {
        const int k = i * 4 + tr;
        dst[(size_t)(proj * 1024 + h * 64 + k) * DIM + r0 + tc] = __float2bfloat16(tile[tc][k]);
    }
}

// ---------------------------------------------------------------------------
// bf16 GEMM  C[M,N] = A[M,K] * Bt[N,K]^T   (m97 structure)
// EPI 0: outb = bf16(acc)
// EPI 1: outb = bf16(gelu(acc + bias[col]))
// EPI 2: outf = resid + acc + bias[col]   (fp32)
// ---------------------------------------------------------------------------
template <int EPI>
__global__ __launch_bounds__(256) void gemm_bt(const __hip_bfloat16* __restrict__ A,
                                               const __hip_bfloat16* __restrict__ Bt,
                                               __hip_bfloat16* __restrict__ outb,
                                               float* __restrict__ outf,
                                               const float* __restrict__ bias,
                                               const float* __restrict__ resid,
                                               int M, int N, int K) {
    __shared__ __align__(16) __hip_bfloat16 As[128 * 32];
    __shared__ __align__(16) __hip_bfloat16 Bs[128 * 32];
    const int t = threadIdx.x;
    const int w = t >> 6, l = t & 63;
    const int quad = l >> 4, tl = l & 15;
    const int wr = w >> 1, wc = w & 1;
    const int m0 = blockIdx.y * 128, n0 = blockIdx.x * 128;

    floatx4 acc[4][4] = {};

    const int rowA = t >> 2;
    const int c8 = (t & 3) << 3;

    for (int k0 = 0; k0 < K; k0 += 32) {
        __syncthreads();
        {
            const __hip_bfloat16* gA = A + (size_t)(m0 + rowA) * K + k0 + c8;
            const __hip_bfloat16* gB = Bt + (size_t)(n0 + rowA) * K + k0 + c8;
            async_copy16(gA,                    As + w * 512);
            async_copy16(gA + (size_t)64 * K,   As + 2048 + w * 512);
            async_copy16(gB,                    Bs + w * 512);
            async_copy16(gB + (size_t)64 * K,   Bs + 2048 + w * 512);
        }
        __syncthreads();

        bf16x8 af[4], bfr[4];
        const int aRow = wr * 64 + tl;
        const int bRow = wc * 64 + tl;
        for (int mi = 0; mi < 4; ++mi)
            af[mi] = *(const bf16x8*)(As + (aRow + mi * 16) * 32 + quad * 8);
        for (int ni = 0; ni < 4; ++ni)
            bfr[ni] = *(const bf16x8*)(Bs + (bRow + ni * 16) * 32 + quad * 8);
        for (int mi = 0; mi < 4; ++mi)
            for (int ni = 0; ni < 4; ++ni)
                acc[mi][ni] = __builtin_amdgcn_mfma_f32_16x16x32_bf16(af[mi], bfr[ni], acc[mi][ni], 0, 0, 0);
    }

    const int rowBase = m0 + wr * 64 + quad * 4;
    const int colBase = n0 + wc * 64 + tl;
    for (int mi = 0; mi < 4; ++mi) {
        for (int ni = 0; ni < 4; ++ni) {
            const int c = colBase + ni * 16;
            for (int j = 0; j < 4; ++j) {
                const int r = rowBase + mi * 16 + j;
                const size_t idx = (size_t)r * N + c;
                float v = acc[mi][ni][j];
                if (EPI == 0) {
                    outb[idx] = __float2bfloat16(v);
                } else if (EPI == 1) {
                    v += bias[c];
                    v = 0.5f * v * (1.0f + erff(v * 0.70710678118654752f));
                    outb[idx] = __float2bfloat16(v);
                } else {
                    outf[idx] = resid[idx] + v + bias[c];
                }
            }
        }
    }
}

// ---------------------------------------------------------------------------
// Flash causal attention, LDS-staged K/V.
// One workgroup (4 waves) per (b, h, 64 q-rows); wave w owns rows [q0+16w, +16).
// K-block loop over 64 keys: cooperative coalesced staging into LDS
// (Ks stride 72: conflict-free b128 reads; Vs stride 76: 2-way scalar reads),
// QK^T MFMA -> online softmax (exp2 domain) -> P via per-wave LDS -> PV MFMA.
// Diagonal block: wave w computes only ni<=w score tiles (triangular skip).
// ---------------------------------------------------------------------------
#define KS_LD 72
#define VS_LD 76
#define PL_LD 72
__global__ __launch_bounds__(256) void attn_kernel(const __hip_bfloat16* __restrict__ qkv,
                                                   __hip_bfloat16* __restrict__ out) {
    __shared__ __align__(16) __hip_bfloat16 Ks[64 * KS_LD];
    __shared__ __align__(16) __hip_bfloat16 Vs[64 * VS_LD];
    __shared__ __align__(16) __hip_bfloat16 Pl[4][16 * PL_LD];
    const int t = threadIdx.x;
    const int w = t >> 6, l = t & 63;
    const int quad = l >> 4, tl = l & 15;
    const int qb = blockIdx.x & 31;        // q block of 64 rows
    const int bh = blockIdx.x >> 5;        // 0..31
    const int b = bh >> 4, h = bh & 15;
    const int q0 = qb * 64;
    const int qw = q0 + w * 16;            // this wave's q-row base
    const size_t base = (size_t)b * TSEQ * QKV_LD + h * HDIM;
    const __hip_bfloat16* Qp = qkv + base;
    const __hip_bfloat16* Kp = Qp + 1024;
    const __hip_bfloat16* Vp = Qp + 2048;

    // Q fragments for this wave's 16 rows (A operand: row=tl, k=quad*8+j)
    const __hip_bfloat16* qrow = Qp + (size_t)(qw + tl) * QKV_LD + quad * 8;
    const bf16x8 qf0 = *(const bf16x8*)qrow;
    const bf16x8 qf1 = *(const bf16x8*)(qrow + 32);

    float m_i[4], l_i[4];
    floatx4 oacc[4] = {};
    for (int j = 0; j < 4; ++j) { m_i[j] = -1e30f; l_i[j] = 0.0f; }
    const float cscale = 0.125f * 1.4426950408889634f;  // K^-0.5 * log2(e)
    const int nblk = qb + 1;
    __hip_bfloat16* P = Pl[w];

    for (int it = 0; it < nblk; ++it) {
        const int s0 = it * 64;
        __syncthreads();   // all waves done reading previous Ks/Vs
        // cooperative staging: 64 rows x 64 cols of K and V (coalesced 16B/lane)
        for (int i = 0; i < 2; ++i) {
            const int c = i * 256 + t;
            const int r = c >> 3, k8 = c & 7;
            const bf16x8 kv = *(const bf16x8*)(Kp + (size_t)(s0 + r) * QKV_LD + k8 * 8);
            const bf16x8 vv = *(const bf16x8*)(Vp + (size_t)(s0 + r) * QKV_LD + k8 * 8);
            *(bf16x8*)(Ks + r * KS_LD + k8 * 8) = kv;
            __hip_bfloat16* vd = Vs + r * VS_LD + k8 * 8;
            *(bf16x4*)vd       = bf16x4{vv[0], vv[1], vv[2], vv[3]};
            *(bf16x4*)(vd + 4) = bf16x4{vv[4], vv[5], vv[6], vv[7]};
        }
        __syncthreads();

        const bool last = (it == nblk - 1);
        const int nact = last ? (w + 1) : 4;     // active 16-key tiles this wave

        // QK^T: 16 q-rows x 64 keys (only active tiles)
        floatx4 sc[4] = {};
        for (int ni = 0; ni < nact; ++ni) {
            const __hip_bfloat16* kr = Ks + (ni * 16 + tl) * KS_LD + quad * 8;
            const bf16x8 kfa = *(const bf16x8*)kr;
            const bf16x8 kfb = *(const bf16x8*)(kr + 32);
            sc[ni] = __builtin_amdgcn_mfma_f32_16x16x32_bf16(qf0, kfa, sc[ni], 0, 0, 0);
            sc[ni] = __builtin_amdgcn_mfma_f32_16x16x32_bf16(qf1, kfb, sc[ni], 0, 0, 0);
        }

        // online softmax per q-row j (C-layout: row=quad*4+j, col=ni*16+tl)
        float alpha[4];
        float p[4][4];   // [j][ni]
        for (int j = 0; j < 4; ++j) {
            float vv[4];
            for (int ni = 0; ni < 4; ++ni) {
                float s = (ni < nact) ? sc[ni][j] * cscale : -1e30f;
                if (last && ni == w && tl > quad * 4 + j) s = -1e30f;  // diagonal mask
                vv[ni] = s;
            }
            float tm = fmaxf(fmaxf(vv[0], vv[1]), fmaxf(vv[2], vv[3]));
            tm = fmaxf(tm, __shfl_xor(tm, 1));
            tm = fmaxf(tm, __shfl_xor(tm, 2));
            tm = fmaxf(tm, __shfl_xor(tm, 4));
            tm = fmaxf(tm, __shfl_xor(tm, 8));
            const float mn = fmaxf(m_i[j], tm);
            alpha[j] = exp2f(m_i[j] - mn);
            m_i[j] = mn;
            float ps = 0.0f;
            for (int ni = 0; ni < 4; ++ni) {
                p[j][ni] = exp2f(vv[ni] - mn);
                ps += p[j][ni];
            }
            ps += __shfl_xor(ps, 1);
            ps += __shfl_xor(ps, 2);
            ps += __shfl_xor(ps, 4);
            ps += __shfl_xor(ps, 8);
            l_i[j] = l_i[j] * alpha[j] + ps;
        }
        for (int ni = 0; ni < 4; ++ni)
            for (int j = 0; j < 4; ++j)
                oacc[ni][j] *= alpha[j];

        // P (C-layout) -> per-wave LDS -> A-layout fragments
        for (int j = 0; j < 4; ++j)
            for (int ni = 0; ni < 4; ++ni)
                P[(quad * 4 + j) * PL_LD + ni * 16 + tl] = __float2bfloat16(p[j][ni]);
        __builtin_amdgcn_wave_barrier();

        const int kcmax = (nact + 1) >> 1;   // 32-key chunks with any active P
        for (int kc = 0; kc < kcmax; ++kc) {
            const bf16x8 pf = *(const bf16x8*)(P + tl * PL_LD + kc * 32 + quad * 8);
            for (int ni = 0; ni < 4; ++ni) {
                bf16x8 vf;
                const unsigned short* vs = (const unsigned short*)
                    (Vs + (kc * 32 + quad * 8) * VS_LD + ni * 16 + tl);
                for (int jj = 0; jj < 8; ++jj)
                    vf[jj] = (short)vs[(size_t)jj * VS_LD];
                oacc[ni] = __builtin_amdgcn_mfma_f32_16x16x32_bf16(pf, vf, oacc[ni], 0, 0, 0);
            }
        }
    }

    for (int j = 0; j < 4; ++j) {
        const float inv = 1.0f / l_i[j];
        const int r = qw + quad * 4 + j;
        __hip_bfloat16* orow = out + ((size_t)b * TSEQ + r) * DIM + h * HDIM;
        for (int ni = 0; ni < 4; ++ni)
            orow[ni * 16 + tl] = __float2bfloat16(oacc[ni][j] * inv);
    }
}

// ---------------------------------------------------------------------------
extern "C" void kernel_launch(void* const* d_in, const int* in_sizes, int n_in,
                              void* d_out, int out_size, void* d_ws, size_t ws_size,
                              hipStream_t stream) {
    const float* x   = (const float*)d_in[0];
    const float* Wq  = (const float*)d_in[1];
    const float* Wk  = (const float*)d_in[2];
    const float* Wv  = (const float*)d_in[3];
    const float* Wo  = (const float*)d_in[4];
    const float* bo  = (const float*)d_in[5];
    const float* W1  = (const float*)d_in[6];
    const float* b1  = (const float*)d_in[7];
    const float* W2  = (const float*)d_in[8];
    const float* b2  = (const float*)d_in[9];
    const float* g1  = (const float*)d_in[10];
    const float* be1 = (const float*)d_in[11];
    const float* g2  = (const float*)d_in[12];
    const float* be2 = (const float*)d_in[13];
    float* out = (float*)d_out;

    size_t off = 0;
    char* wsb = (char*)d_ws;
    auto carve = [&](size_t bytes) {
        void* p = wsb + off;
        off += (bytes + 255) & ~(size_t)255;
        return p;
    };
    __hip_bfloat16* WqkvT = (__hip_bfloat16*)carve((size_t)3072 * 1024 * 2);
    __hip_bfloat16* WoT   = (__hip_bfloat16*)carve((size_t)1024 * 1024 * 2);
    __hip_bfloat16* W1T   = (__hip_bfloat16*)carve((size_t)4096 * 1024 * 2);
    __hip_bfloat16* W2T   = (__hip_bfloat16*)carve((size_t)1024 * 4096 * 2);
    __hip_bfloat16* h1    = (__hip_bfloat16*)carve((size_t)BT * DIM * 2);
    __hip_bfloat16* qkv   = (__hip_bfloat16*)carve((size_t)BT * QKV_LD * 2);
    __hip_bfloat16* att   = (__hip_bfloat16*)carve((size_t)BT * DIM * 2);
    float*          x2    = (float*)carve((size_t)BT * DIM * 4);
    __hip_bfloat16* h2    = (__hip_bfloat16*)carve((size_t)BT * DIM * 2);
    __hip_bfloat16* ff1   = (__hip_bfloat16*)carve((size_t)BT * DFF * 2);

    // weight prep
    transpose_qkv<<<dim3(16, 48), 256, 0, stream>>>(Wq, Wk, Wv, WqkvT);
    transpose_cast<<<dim3(16, 16), 256, 0, stream>>>(Wo, 1024, WoT, 1024);
    transpose_cast<<<dim3(16, 64), 256, 0, stream>>>(W1, 4096, W1T, 1024);
    transpose_cast<<<dim3(64, 16), 256, 0, stream>>>(W2, 1024, W2T, 4096);

    // LN1
    ln_kernel<<<BT, 256, 0, stream>>>(x, g1, be1, h1);
    // fused QKV projection: [4096,1024] x [3072,1024]^T -> bf16 [4096,3072]
    gemm_bt<0><<<dim3(24, 32), 256, 0, stream>>>(h1, WqkvT, qkv, nullptr, nullptr, nullptr,
                                                 BT, QKV_LD, DIM);
    // causal MHA
    attn_kernel<<<1024, 256, 0, stream>>>(qkv, att);
    // x2 = x + att @ Wo + bo   (fp32)
    gemm_bt<2><<<dim3(8, 32), 256, 0, stream>>>(att, WoT, nullptr, x2, bo, x,
                                                BT, DIM, DIM);
    // LN2
    ln_kernel<<<BT, 256, 0, stream>>>(x2, g2, be2, h2);
    // ff = gelu(h2 @ W1 + b1)  bf16 [4096,4096]
    gemm_bt<1><<<dim3(32, 32), 256, 0, stream>>>(h2, W1T, ff1, nullptr, b1, nullptr,
                                                 BT, DFF, DIM);
    // out = x2 + ff @ W2 + b2  (fp32)
    gemm_bt<2><<<dim3(8, 32), 256, 0, stream>>>(ff1, W2T, nullptr, out, b2, x2,
                                                BT, DIM, DFF);
}

// Round 3
// 476.134 us; speedup vs baseline: 1.1522x; 1.0877x over previous
//
#include <hip/hip_runtime.h>
#include <hip/hip_bf16.h>

// ---------------------------------------------------------------------------
// TransformerBlock: LN1 -> fused QKV GEMM -> flash causal MHA -> Wo GEMM (+x)
//                   -> LN2 -> FF1 GEMM (+b1, exact GELU) -> FF2 GEMM (+x2)
// B=2, T=2048, D=1024, H=16, K=64, DFF=4096. fp32 I/O, bf16 MFMA internally.
// ---------------------------------------------------------------------------

#define BT   4096   // B*T rows
#define DIM  1024
#define DFF  4096
#define TSEQ 2048
#define NHEAD 16
#define HDIM 64
#define QKV_LD 3072

typedef __attribute__((ext_vector_type(8))) short  bf16x8;
typedef __attribute__((ext_vector_type(4))) float  floatx4;

__device__ __forceinline__ void async_copy16(const __hip_bfloat16* g, __hip_bfloat16* l) {
    __builtin_amdgcn_global_load_lds(
        (const __attribute__((address_space(1))) void*)g,
        (__attribute__((address_space(3))) void*)l, 16, 0, 0);
}

__device__ __forceinline__ floatx4 mfma_bf16(bf16x8 a, bf16x8 b, floatx4 c) {
    return __builtin_amdgcn_mfma_f32_16x16x32_bf16(a, b, c, 0, 0, 0);
}

// ---------------------------------------------------------------------------
// LayerNorm: fp32 in -> bf16 out.  One block (256 thr) per row of 1024.
// ---------------------------------------------------------------------------
__global__ __launch_bounds__(256) void ln_kernel(const float* __restrict__ x,
                                                 const float* __restrict__ g,
                                                 const float* __restrict__ be,
                                                 __hip_bfloat16* __restrict__ out) {
    const int row = blockIdx.x;
    const int t = threadIdx.x;
    const float4 v = ((const float4*)(x + (size_t)row * DIM))[t];
    float s  = v.x + v.y + v.z + v.w;
    float ss = v.x * v.x + v.y * v.y + v.z * v.z + v.w * v.w;
    for (int d = 1; d < 64; d <<= 1) { s += __shfl_xor(s, d); ss += __shfl_xor(ss, d); }
    __shared__ float red[8];
    const int w = t >> 6;
    if ((t & 63) == 0) { red[w] = s; red[w + 4] = ss; }
    __syncthreads();
    s  = red[0] + red[1] + red[2] + red[3];
    ss = red[4] + red[5] + red[6] + red[7];
    const float mu = s * (1.0f / DIM);
    const float rstd = rsqrtf(ss * (1.0f / DIM) - mu * mu + 1e-5f);
    const float4 gv = ((const float4*)g)[t];
    const float4 bv = ((const float4*)be)[t];
    __hip_bfloat16* o = out + (size_t)row * DIM + t * 4;
    o[0] = __float2bfloat16((v.x - mu) * rstd * gv.x + bv.x);
    o[1] = __float2bfloat16((v.y - mu) * rstd * gv.y + bv.y);
    o[2] = __float2bfloat16((v.z - mu) * rstd * gv.z + bv.z);
    o[3] = __float2bfloat16((v.w - mu) * rstd * gv.w + bv.w);
}

// ---------------------------------------------------------------------------
// Generic 64x64-tile transpose+cast: dst[c][r] = (bf16)src[r][c]
// ---------------------------------------------------------------------------
__global__ __launch_bounds__(256) void transpose_cast(const float* __restrict__ src, int src_ld,
                                                      __hip_bfloat16* __restrict__ dst, int dst_ld) {
    __shared__ float tile[64][65];
    const int r0 = blockIdx.x * 64, c0 = blockIdx.y * 64;
    const int tr = threadIdx.x >> 6;   // 0..3
    const int tc = threadIdx.x & 63;   // 0..63
    for (int i = 0; i < 16; ++i) {
        const int r = i * 4 + tr;
        tile[r][tc] = src[(size_t)(r0 + r) * src_ld + c0 + tc];
    }
    __syncthreads();
    for (int i = 0; i < 16; ++i) {
        const int c = i * 4 + tr;
        dst[(size_t)(c0 + c) * dst_ld + r0 + tc] = __float2bfloat16(tile[tc][c]);
    }
}

// Wq/Wk/Wv [H][D][64] fp32 -> WqkvT [3072][1024] bf16, row n = proj*1024+h*64+k
__global__ __launch_bounds__(256) void transpose_qkv(const float* __restrict__ Wq,
                                                     const float* __restrict__ Wk,
                                                     const float* __restrict__ Wv,
                                                     __hip_bfloat16* __restrict__ dst) {
    __shared__ float tile[64][65];
    const int hz = blockIdx.y;            // 0..47
    const int proj = hz >> 4, h = hz & 15;
    const float* W = (proj == 0 ? Wq : (proj == 1 ? Wk : Wv)) + (size_t)h * DIM * HDIM;
    const int r0 = blockIdx.x * 64;       // d tile
    const int tr = threadIdx.x >> 6;
    const int tc = threadIdx.x & 63;
    for (int i = 0; i < 16; ++i) {
        const int r = i * 4 + tr;
        tile[r][tc] = W[(size_t)(r0 + r) * HDIM + tc];
    }
    __syncthreads();
    for (int i = 0; i < 16; ++i) {
        const int k = i * 4 + tr;
        dst[(size_t)(proj * 1024 + h * 64 + k) * DIM + r0 + tc] = __float2bfloat16(tile[tc][k]);
    }
}

// ---------------------------------------------------------------------------
// V transpose: qkv V-block [T][64] per (b,h) -> Vt[bh][64 d][2048 t] bf16.
// XOR column-block swizzle in LDS keeps both sides coalesced / low-conflict.
// ---------------------------------------------------------------------------
__global__ __launch_bounds__(256) void transpose_v(const __hip_bfloat16* __restrict__ qkv,
                                                   __hip_bfloat16* __restrict__ vt) {
    __shared__ __align__(16) __hip_bfloat16 tile[64 * 72];
    const int t = threadIdx.x;
    const int bh = blockIdx.y;            // 0..31
    const int b = bh >> 4, h = bh & 15;
    const int t0 = blockIdx.x * 64;
    const __hip_bfloat16* src = qkv + (size_t)b * TSEQ * QKV_LD + 2048 + h * HDIM;
    const int lo = t >> 3, k8 = t & 7;
    for (int i = 0; i < 2; ++i) {
        const int rr = i * 32 + lo;       // key row
        const bf16x8 v = *(const bf16x8*)(src + (size_t)(t0 + rr) * QKV_LD + k8 * 8);
        const int cb = k8 ^ ((rr >> 3) & 7);   // swizzled column block
        *(bf16x8*)(tile + rr * 72 + cb * 8) = v;
    }
    __syncthreads();
    for (int i = 0; i < 2; ++i) {
        const int dd = i * 32 + lo;       // hdim row of Vt
        const int c0 = dd >> 3, cl = dd & 7;
        bf16x8 o;
        for (int jj = 0; jj < 8; ++jj) {
            const int key = k8 * 8 + jj;
            o[jj] = *(const short*)(tile + key * 72 + (c0 ^ ((key >> 3) & 7)) * 8 + cl);
        }
        *(bf16x8*)(vt + ((size_t)bh * HDIM + dd) * TSEQ + t0 + k8 * 8) = o;
    }
}

// ---------------------------------------------------------------------------
// bf16 GEMM  C[M,N] = A[M,K] * Bt[N,K]^T   (m97 structure, 128x128 tile)
// EPI 0: outb = bf16(acc);  EPI 1: outb = bf16(gelu(acc + bias[col]))
// ---------------------------------------------------------------------------
template <int EPI>
__global__ __launch_bounds__(256) void gemm_bt(const __hip_bfloat16* __restrict__ A,
                                               const __hip_bfloat16* __restrict__ Bt,
                                               __hip_bfloat16* __restrict__ outb,
                                               const float* __restrict__ bias,
                                               int M, int N, int K) {
    __shared__ __align__(16) __hip_bfloat16 As[128 * 32];
    __shared__ __align__(16) __hip_bfloat16 Bs[128 * 32];
    const int t = threadIdx.x;
    const int w = t >> 6, l = t & 63;
    const int quad = l >> 4, tl = l & 15;
    const int wr = w >> 1, wc = w & 1;
    const int m0 = blockIdx.y * 128, n0 = blockIdx.x * 128;

    floatx4 acc[4][4] = {};
    const int rowA = t >> 2;
    const int c8 = (t & 3) << 3;

    for (int k0 = 0; k0 < K; k0 += 32) {
        __syncthreads();
        {
            const __hip_bfloat16* gA = A + (size_t)(m0 + rowA) * K + k0 + c8;
            const __hip_bfloat16* gB = Bt + (size_t)(n0 + rowA) * K + k0 + c8;
            async_copy16(gA,                  As + w * 512);
            async_copy16(gA + (size_t)64 * K, As + 2048 + w * 512);
            async_copy16(gB,                  Bs + w * 512);
            async_copy16(gB + (size_t)64 * K, Bs + 2048 + w * 512);
        }
        __syncthreads();

        bf16x8 af[4], bfr[4];
        const int aRow = wr * 64 + tl;
        const int bRow = wc * 64 + tl;
        for (int mi = 0; mi < 4; ++mi)
            af[mi] = *(const bf16x8*)(As + (aRow + mi * 16) * 32 + quad * 8);
        for (int ni = 0; ni < 4; ++ni)
            bfr[ni] = *(const bf16x8*)(Bs + (bRow + ni * 16) * 32 + quad * 8);
        for (int mi = 0; mi < 4; ++mi)
            for (int ni = 0; ni < 4; ++ni)
                acc[mi][ni] = mfma_bf16(af[mi], bfr[ni], acc[mi][ni]);
    }

    const int rowBase = m0 + wr * 64 + quad * 4;
    const int colBase = n0 + wc * 64 + tl;
    for (int mi = 0; mi < 4; ++mi) {
        for (int ni = 0; ni < 4; ++ni) {
            const int c = colBase + ni * 16;
            for (int j = 0; j < 4; ++j) {
                const int r = rowBase + mi * 16 + j;
                const size_t idx = (size_t)r * N + c;
                float v = acc[mi][ni][j];
                if (EPI == 1) {
                    v += bias[c];
                    v = 0.5f * v * (1.0f + erff(v * 0.70710678118654752f));
                }
                outb[idx] = __float2bfloat16(v);
            }
        }
    }
}

// ---------------------------------------------------------------------------
// bf16 GEMM, 128x64 tile, fp32 epilogue: outf = resid + acc + bias[col].
// For N=1024 GEMMs (Wo, FF2) where the 128x128 grid starves the CUs.
// ---------------------------------------------------------------------------
__global__ __launch_bounds__(256) void gemm_bt_n64(const __hip_bfloat16* __restrict__ A,
                                                   const __hip_bfloat16* __restrict__ Bt,
                                                   float* __restrict__ outf,
                                                   const float* __restrict__ bias,
                                                   const float* __restrict__ resid,
                                                   int M, int N, int K) {
    __shared__ __align__(16) __hip_bfloat16 As[128 * 32];
    __shared__ __align__(16) __hip_bfloat16 Bs[64 * 32];
    const int t = threadIdx.x;
    const int w = t >> 6, l = t & 63;
    const int quad = l >> 4, tl = l & 15;
    const int m0 = blockIdx.y * 128, n0 = blockIdx.x * 64;

    floatx4 acc[2][4] = {};
    const int rowA = t >> 2;
    const int c8 = (t & 3) << 3;

    for (int k0 = 0; k0 < K; k0 += 32) {
        __syncthreads();
        {
            const __hip_bfloat16* gA = A + (size_t)(m0 + rowA) * K + k0 + c8;
            const __hip_bfloat16* gB = Bt + (size_t)(n0 + rowA) * K + k0 + c8;
            async_copy16(gA,                  As + w * 512);
            async_copy16(gA + (size_t)64 * K, As + 2048 + w * 512);
            async_copy16(gB,                  Bs + w * 512);
        }
        __syncthreads();

        bf16x8 af[2], bfr[4];
        for (int mi = 0; mi < 2; ++mi)
            af[mi] = *(const bf16x8*)(As + (w * 32 + mi * 16 + tl) * 32 + quad * 8);
        for (int ni = 0; ni < 4; ++ni)
            bfr[ni] = *(const bf16x8*)(Bs + (ni * 16 + tl) * 32 + quad * 8);
        for (int mi = 0; mi < 2; ++mi)
            for (int ni = 0; ni < 4; ++ni)
                acc[mi][ni] = mfma_bf16(af[mi], bfr[ni], acc[mi][ni]);
    }

    const int rowBase = m0 + w * 32 + quad * 4;
    const int colBase = n0 + tl;
    for (int mi = 0; mi < 2; ++mi) {
        for (int ni = 0; ni < 4; ++ni) {
            const int c = colBase + ni * 16;
            for (int j = 0; j < 4; ++j) {
                const int r = rowBase + mi * 16 + j;
                const size_t idx = (size_t)r * N + c;
                outf[idx] = resid[idx] + acc[mi][ni][j] + bias[c];
            }
        }
    }
}

// ---------------------------------------------------------------------------
// Flash causal attention, LDS-staged K and pre-transposed Vt.
// One workgroup (4 waves) per (b, h, 64 q-rows); wave w owns rows [q0+16w,+16).
// Heavy-first qb ordering for load balance. Softmax: batched shuffle-max
// (4 independent bpermute per round), per-lane l partials (reduced once at end).
// ---------------------------------------------------------------------------
#define KS_LD 72
#define VT_LD 72
#define PL_LD 72
__global__ __launch_bounds__(256) void attn_kernel(const __hip_bfloat16* __restrict__ qkv,
                                                   const __hip_bfloat16* __restrict__ vt,
                                                   __hip_bfloat16* __restrict__ out) {
    __shared__ __align__(16) __hip_bfloat16 Ks[64 * KS_LD];
    __shared__ __align__(16) __hip_bfloat16 Vts[64 * VT_LD];
    __shared__ __align__(16) __hip_bfloat16 Pl[4][16 * PL_LD];
    const int t = threadIdx.x;
    const int w = t >> 6, l = t & 63;
    const int quad = l >> 4, tl = l & 15;
    const int qb = 31 - (blockIdx.x & 31);   // heavy-first
    const int bh = blockIdx.x >> 5;          // 0..31
    const int b = bh >> 4, h = bh & 15;
    const int qw = qb * 64 + w * 16;         // this wave's q-row base
    const __hip_bfloat16* Qp  = qkv + (size_t)b * TSEQ * QKV_LD + h * HDIM;
    const __hip_bfloat16* Kp  = Qp + 1024;
    const __hip_bfloat16* Vtp = vt + (size_t)bh * HDIM * TSEQ;

    // Q fragments (A operand: row=tl, k=quad*8+j)
    const __hip_bfloat16* qrow = Qp + (size_t)(qw + tl) * QKV_LD + quad * 8;
    const bf16x8 qf0 = *(const bf16x8*)qrow;
    const bf16x8 qf1 = *(const bf16x8*)(qrow + 32);

    float m_i[4], l_i[4];
    floatx4 oacc[4] = {};
    for (int j = 0; j < 4; ++j) { m_i[j] = -1e30f; l_i[j] = 0.0f; }
    const float cscale = 0.125f * 1.4426950408889634f;  // K^-0.5 * log2(e)
    const int nblk = qb + 1;
    __hip_bfloat16* P = Pl[w];
    const int srow = t >> 3, sk8 = t & 7;

    for (int it = 0; it < nblk; ++it) {
        const int s0 = it * 64;
        __syncthreads();   // all waves done reading previous Ks/Vts
        for (int i = 0; i < 2; ++i) {
            const int rr = i * 32 + srow;
            const bf16x8 kv = *(const bf16x8*)(Kp  + (size_t)(s0 + rr) * QKV_LD + sk8 * 8);
            const bf16x8 vv = *(const bf16x8*)(Vtp + (size_t)rr * TSEQ + s0 + sk8 * 8);
            *(bf16x8*)(Ks  + rr * KS_LD + sk8 * 8) = kv;
            *(bf16x8*)(Vts + rr * VT_LD + sk8 * 8) = vv;
        }
        __syncthreads();

        const bool last = (it == nblk - 1);
        const int nact = last ? (w + 1) : 4;     // active 16-key tiles this wave

        // QK^T: 16 q-rows x 64 keys
        floatx4 sc[4];
        for (int ni = 0; ni < nact; ++ni) {
            sc[ni] = floatx4{0.0f, 0.0f, 0.0f, 0.0f};
            const __hip_bfloat16* kr = Ks + (ni * 16 + tl) * KS_LD + quad * 8;
            sc[ni] = mfma_bf16(qf0, *(const bf16x8*)kr,        sc[ni]);
            sc[ni] = mfma_bf16(qf1, *(const bf16x8*)(kr + 32), sc[ni]);
        }

        // scale + mask + per-lane max (C-layout: row=quad*4+j, col=ni*16+tl)
        float pj[4][4], mx[4];
        for (int j = 0; j < 4; ++j) {
            for (int ni = 0; ni < 4; ++ni) {
                float s = (ni < nact) ? sc[ni][j] * cscale : -1e30f;
                if (last && ni == w && tl > quad * 4 + j) s = -1e30f;
                pj[j][ni] = s;
            }
            mx[j] = fmaxf(fmaxf(pj[j][0], pj[j][1]), fmaxf(pj[j][2], pj[j][3]));
        }
        // batched 16-lane max reduce: 4 independent bpermutes per round
        for (int d = 1; d < 16; d <<= 1) {
            float r0 = __shfl_xor(mx[0], d), r1 = __shfl_xor(mx[1], d);
            float r2 = __shfl_xor(mx[2], d), r3 = __shfl_xor(mx[3], d);
            mx[0] = fmaxf(mx[0], r0); mx[1] = fmaxf(mx[1], r1);
            mx[2] = fmaxf(mx[2], r2); mx[3] = fmaxf(mx[3], r3);
        }
        float alpha[4];
        for (int j = 0; j < 4; ++j) {
            const float mn = fmaxf(m_i[j], mx[j]);
            alpha[j] = exp2f(m_i[j] - mn);
            m_i[j] = mn;
            float ps = 0.0f;
            for (int ni = 0; ni < 4; ++ni) {
                pj[j][ni] = exp2f(pj[j][ni] - mn);
                ps += pj[j][ni];
            }
            l_i[j] = l_i[j] * alpha[j] + ps;   // per-lane partial (exact: alpha row-uniform)
        }
        for (int ni = 0; ni < 4; ++ni)
            for (int j = 0; j < 4; ++j)
                oacc[ni][j] *= alpha[j];

        // P (C-layout) -> per-wave LDS -> A-layout fragments
        for (int j = 0; j < 4; ++j)
            for (int ni = 0; ni < 4; ++ni)
                P[(quad * 4 + j) * PL_LD + ni * 16 + tl] = __float2bfloat16(pj[j][ni]);
        __builtin_amdgcn_wave_barrier();

        const int kcmax = (nact + 1) >> 1;
        for (int kc = 0; kc < kcmax; ++kc) {
            const bf16x8 pf = *(const bf16x8*)(P + tl * PL_LD + kc * 32 + quad * 8);
            for (int ni = 0; ni < 4; ++ni) {
                const bf16x8 vf = *(const bf16x8*)(Vts + (ni * 16 + tl) * VT_LD + kc * 32 + quad * 8);
                oacc[ni] = mfma_bf16(pf, vf, oacc[ni]);
            }
        }
    }

    // deferred l reduction (16 lanes), batched
    for (int d = 1; d < 16; d <<= 1) {
        float r0 = __shfl_xor(l_i[0], d), r1 = __shfl_xor(l_i[1], d);
        float r2 = __shfl_xor(l_i[2], d), r3 = __shfl_xor(l_i[3], d);
        l_i[0] += r0; l_i[1] += r1; l_i[2] += r2; l_i[3] += r3;
    }
    for (int j = 0; j < 4; ++j) {
        const float inv = 1.0f / l_i[j];
        const int r = qw + quad * 4 + j;
        __hip_bfloat16* orow = out + ((size_t)b * TSEQ + r) * DIM + h * HDIM;
        for (int ni = 0; ni < 4; ++ni)
            orow[ni * 16 + tl] = __float2bfloat16(oacc[ni][j] * inv);
    }
}

// ---------------------------------------------------------------------------
extern "C" void kernel_launch(void* const* d_in, const int* in_sizes, int n_in,
                              void* d_out, int out_size, void* d_ws, size_t ws_size,
                              hipStream_t stream) {
    const float* x   = (const float*)d_in[0];
    const float* Wq  = (const float*)d_in[1];
    const float* Wk  = (const float*)d_in[2];
    const float* Wv  = (const float*)d_in[3];
    const float* Wo  = (const float*)d_in[4];
    const float* bo  = (const float*)d_in[5];
    const float* W1  = (const float*)d_in[6];
    const float* b1  = (const float*)d_in[7];
    const float* W2  = (const float*)d_in[8];
    const float* b2  = (const float*)d_in[9];
    const float* g1  = (const float*)d_in[10];
    const float* be1 = (const float*)d_in[11];
    const float* g2  = (const float*)d_in[12];
    const float* be2 = (const float*)d_in[13];
    float* out = (float*)d_out;

    size_t off = 0;
    char* wsb = (char*)d_ws;
    auto carve = [&](size_t bytes) {
        void* p = wsb + off;
        off += (bytes + 255) & ~(size_t)255;
        return p;
    };
    __hip_bfloat16* WqkvT = (__hip_bfloat16*)carve((size_t)3072 * 1024 * 2);
    __hip_bfloat16* WoT   = (__hip_bfloat16*)carve((size_t)1024 * 1024 * 2);
    __hip_bfloat16* W1T   = (__hip_bfloat16*)carve((size_t)4096 * 1024 * 2);
    __hip_bfloat16* W2T   = (__hip_bfloat16*)carve((size_t)1024 * 4096 * 2);
    __hip_bfloat16* h1    = (__hip_bfloat16*)carve((size_t)BT * DIM * 2);
    __hip_bfloat16* qkv   = (__hip_bfloat16*)carve((size_t)BT * QKV_LD * 2);
    __hip_bfloat16* vtb   = (__hip_bfloat16*)carve((size_t)BT * DIM * 2);
    __hip_bfloat16* att   = (__hip_bfloat16*)carve((size_t)BT * DIM * 2);
    float*          x2    = (float*)carve((size_t)BT * DIM * 4);
    __hip_bfloat16* h2    = (__hip_bfloat16*)carve((size_t)BT * DIM * 2);
    __hip_bfloat16* ff1   = (__hip_bfloat16*)carve((size_t)BT * DFF * 2);

    // weight prep
    transpose_qkv<<<dim3(16, 48), 256, 0, stream>>>(Wq, Wk, Wv, WqkvT);
    transpose_cast<<<dim3(16, 16), 256, 0, stream>>>(Wo, 1024, WoT, 1024);
    transpose_cast<<<dim3(16, 64), 256, 0, stream>>>(W1, 4096, W1T, 1024);
    transpose_cast<<<dim3(64, 16), 256, 0, stream>>>(W2, 1024, W2T, 4096);

    // LN1
    ln_kernel<<<BT, 256, 0, stream>>>(x, g1, be1, h1);
    // fused QKV projection: [4096,1024] x [3072,1024]^T -> bf16 [4096,3072]
    gemm_bt<0><<<dim3(24, 32), 256, 0, stream>>>(h1, WqkvT, qkv, nullptr, BT, QKV_LD, DIM);
    // V transpose for attention B-operand
    transpose_v<<<dim3(32, 32), 256, 0, stream>>>(qkv, vtb);
    // causal MHA
    attn_kernel<<<1024, 256, 0, stream>>>(qkv, vtb, att);
    // x2 = x + att @ Wo + bo   (fp32)
    gemm_bt_n64<<<dim3(16, 32), 256, 0, stream>>>(att, WoT, x2, bo, x, BT, DIM, DIM);
    // LN2
    ln_kernel<<<BT, 256, 0, stream>>>(x2, g2, be2, h2);
    // ff = gelu(h2 @ W1 + b1)  bf16 [4096,4096]
    gemm_bt<1><<<dim3(32, 32), 256, 0, stream>>>(h2, W1T, ff1, b1, BT, DFF, DIM);
    // out = x2 + ff @ W2 + b2  (fp32)
    gemm_bt_n64<<<dim3(16, 32), 256, 0, stream>>>(ff1, W2T, out, b2, x2, BT, DIM, DFF);
}